// Round 3
// baseline (1245.123 us; speedup 1.0000x reference)
//
#include <hip/hip_runtime.h>
#include <math.h>

#define NB 2048
#define CINC 10
#define HID 20
#define NG 5
#define GDIM 100   // NG*HID
#define GH 15
#define GW 15
#define BT 8       // batch tile per block

// ---------------- Kernel 1: conv3x3 + bias + maxpool2x2 + tanh ----------------
// x: [B,3,32,32], conv_w: [10,3,3,3], conv_b: [10] -> feat [B,15,15,10]
__global__ __launch_bounds__(256) void conv_pool_tanh(
    const float* __restrict__ x,
    const float* __restrict__ conv_w,
    const float* __restrict__ conv_b,
    float* __restrict__ feat)
{
    __shared__ float wl[270];
    __shared__ float bl[10];
    int tid = threadIdx.x;
    for (int e = tid; e < 270; e += 256) wl[e] = conv_w[e];   // FIX: 270 > blockDim
    if (tid < 10) bl[tid] = conv_b[tid];
    __syncthreads();
    int gid = blockIdx.x * 256 + tid;
    if (gid >= NB * 225) return;
    int b = gid / 225;
    int r = gid % 225;
    int i = r / 15, j = r % 15;
    const float* xb = x + (size_t)b * 3 * 1024;

    float win[3][4][4];
    #pragma unroll
    for (int ic = 0; ic < 3; ++ic)
        #pragma unroll
        for (int rr = 0; rr < 4; ++rr)
            #pragma unroll
            for (int cc = 0; cc < 4; ++cc)
                win[ic][rr][cc] = xb[ic * 1024 + (2 * i + rr) * 32 + (2 * j + cc)];

    float* fo = feat + ((size_t)b * 225 + i * 15 + j) * CINC;
    for (int oc = 0; oc < CINC; ++oc) {
        float a00, a01, a10, a11;
        a00 = a01 = a10 = a11 = bl[oc];
        #pragma unroll
        for (int ic = 0; ic < 3; ++ic)
            #pragma unroll
            for (int kr = 0; kr < 3; ++kr)
                #pragma unroll
                for (int kc = 0; kc < 3; ++kc) {
                    float w = wl[(oc * 3 + ic) * 9 + kr * 3 + kc];
                    a00 += win[ic][kr][kc]         * w;
                    a01 += win[ic][kr][kc + 1]     * w;
                    a10 += win[ic][kr + 1][kc]     * w;
                    a11 += win[ic][kr + 1][kc + 1] * w;
                }
        float m = fmaxf(fmaxf(a00, a01), fmaxf(a10, a11));
        fo[oc] = tanhf(m);
    }
}

// ---------------- Kernel 2: 4-direction MD-LSTM scan ----------------
// One block = (direction, 8-batch tile). 320 threads = (b<8, j<20, s<2).
// s=0: h_up@Whu + Wx[c<5];  s=1: h_left@Whl + Wx[c>=5]. Combine via shfl_xor(1).
// Weights held in registers for the whole 225-cell scan.
__global__ __launch_bounds__(320) void mdlstm_scan(
    const float* __restrict__ feat,   // [B,225,10]
    const float* __restrict__ Wx,     // [4,10,100]
    const float* __restrict__ Whu,    // [4,20,100]
    const float* __restrict__ Whl,    // [4,20,100]
    const float* __restrict__ bg,     // [4,100]
    float* __restrict__ corners)      // [B,80]
{
    int t = threadIdx.x;
    int s = t & 1;
    int j = (t >> 1) % HID;
    int b = t / (2 * HID);            // 0..7
    int d = blockIdx.y;
    int bglob = blockIdx.x * BT + b;
    int fh = (d == 1 || d == 3);
    int fw = (d == 2 || d == 3);

    // ---- load per-thread weights into registers (fixed for whole scan) ----
    float wA[HID][NG];
    const float* WM = (s == 0 ? Whu : Whl) + d * HID * GDIM;
    #pragma unroll
    for (int k = 0; k < HID; ++k)
        #pragma unroll
        for (int g = 0; g < NG; ++g)
            wA[k][g] = WM[k * GDIM + g * HID + j];

    float wX[5][NG];
    const float* WXp = Wx + d * CINC * GDIM + (s ? 5 : 0) * GDIM;
    #pragma unroll
    for (int c = 0; c < 5; ++c)
        #pragma unroll
        for (int g = 0; g < NG; ++g)
            wX[c][g] = WXp[c * GDIM + g * HID + j];

    float bgr[NG];
    #pragma unroll
    for (int g = 0; g < NG; ++g) bgr[g] = bg[d * GDIM + g * HID + j];

    // ---- LDS state ----
    __shared__ float h_up[GW][HID][BT];
    __shared__ float c_up[GW][HID][BT];
    __shared__ float h_lf[HID][BT];
    __shared__ float c_lf[HID][BT];
    __shared__ float fr[GW][BT][CINC];

    for (int e = t; e < GW * HID * BT; e += 320) {
        (&h_up[0][0][0])[e] = 0.f;
        (&c_up[0][0][0])[e] = 0.f;
    }
    __syncthreads();

    for (int i = 0; i < GH; ++i) {
        int fi = fh ? (GH - 1 - i) : i;
        // stage this row's feat (with W-flip applied)
        for (int e = t; e < GW * BT * CINC; e += 320) {
            int col = e / (BT * CINC);
            int rem = e % (BT * CINC);
            int bb  = rem / CINC;
            int c   = rem % CINC;
            int fcol = fw ? (GW - 1 - col) : col;
            fr[col][bb][c] =
                feat[(((size_t)blockIdx.x * BT + bb) * 225 + fi * 15 + fcol) * CINC + c];
        }
        // zero left-state for this row
        for (int e = t; e < HID * BT; e += 320) {
            (&h_lf[0][0])[e] = 0.f;
            (&c_lf[0][0])[e] = 0.f;
        }
        __syncthreads();

        for (int jc = 0; jc < GW; ++jc) {
            // ---- read + accumulate ----
            float acc[NG] = {0.f, 0.f, 0.f, 0.f, 0.f};
            #pragma unroll
            for (int k = 0; k < HID; ++k) {
                float hv = s ? h_lf[k][b] : h_up[jc][k][b];
                #pragma unroll
                for (int g = 0; g < NG; ++g) acc[g] += hv * wA[k][g];
            }
            #pragma unroll
            for (int c = 0; c < 5; ++c) {
                float fv = fr[jc][b][s ? (5 + c) : c];
                #pragma unroll
                for (int g = 0; g < NG; ++g) acc[g] += fv * wX[c][g];
            }
            float cu = c_up[jc][j][b];
            float cl = c_lf[j][b];
            __syncthreads();   // all reads complete before anyone writes

            // ---- combine halves, gates ----
            float tot[NG];
            #pragma unroll
            for (int g = 0; g < NG; ++g)
                tot[g] = acc[g] + __shfl_xor(acc[g], 1) + bgr[g];
            float gi = 1.f / (1.f + expf(-tot[0]));
            float f1 = 1.f / (1.f + expf(-tot[1]));
            float f2 = 1.f / (1.f + expf(-tot[2]));
            float z  = tanhf(tot[3]);
            float go = 1.f / (1.f + expf(-tot[4]));
            float cn = f1 * cu + f2 * cl + gi * z;
            float hn = go * tanhf(cn);

            if (s == 0) {
                h_up[jc][j][b] = hn;
                c_up[jc][j][b] = cn;
                h_lf[j][b] = hn;
                c_lf[j][b] = cn;
            }
            __syncthreads();   // writes visible before next cell reads

            if (s == 0 && i == GH - 1 && jc == GW - 1) {
                corners[(size_t)bglob * 80 + d * HID + j] = hn;
            }
        }
    }
}

// ---------------- Kernel 3: final FC [B,80] @ [80,10] + b ----------------
__global__ __launch_bounds__(256) void fc_kernel(
    const float* __restrict__ corners, // [B,80]
    const float* __restrict__ fc_w,    // [80,10]
    const float* __restrict__ fc_b,    // [10]
    float* __restrict__ out)           // [B,10]
{
    __shared__ float w[800];
    __shared__ float bb[10];
    int t = threadIdx.x;
    for (int e = t; e < 800; e += 256) w[e] = fc_w[e];
    if (t < 10) bb[t] = fc_b[t];
    __syncthreads();
    int gid = blockIdx.x * 256 + t;
    if (gid >= NB * 10) return;
    int b = gid / 10, o = gid % 10;
    float acc = bb[o];
    #pragma unroll 8
    for (int k = 0; k < 80; ++k)
        acc += corners[(size_t)b * 80 + k] * w[k * 10 + o];
    out[gid] = acc;
}

// ---------------- launcher ----------------
extern "C" void kernel_launch(void* const* d_in, const int* in_sizes, int n_in,
                              void* d_out, int out_size, void* d_ws, size_t ws_size,
                              hipStream_t stream) {
    const float* x      = (const float*)d_in[0];
    const float* conv_w = (const float*)d_in[1];
    const float* conv_b = (const float*)d_in[2];
    const float* Wx     = (const float*)d_in[3];
    const float* Whu    = (const float*)d_in[4];
    const float* Whl    = (const float*)d_in[5];
    const float* bg     = (const float*)d_in[6];
    const float* fc_w   = (const float*)d_in[7];
    const float* fc_b   = (const float*)d_in[8];
    float* out = (float*)d_out;

    float* feat    = (float*)d_ws;                     // B*225*10 floats
    float* corners = feat + (size_t)NB * 225 * CINC;   // B*80 floats

    conv_pool_tanh<<<dim3((NB * 225 + 255) / 256), 256, 0, stream>>>(x, conv_w, conv_b, feat);
    mdlstm_scan<<<dim3(NB / BT, 4), 320, 0, stream>>>(feat, Wx, Whu, Whl, bg, corners);
    fc_kernel<<<dim3((NB * 10 + 255) / 256), 256, 0, stream>>>(corners, fc_w, fc_b, out);
}

// Round 6
// 692.781 us; speedup vs baseline: 1.7973x; 1.7973x over previous
//
#include <hip/hip_runtime.h>
#include <math.h>

#define NB 2048
#define CINC 10
#define HID 20
#define NG 5
#define GDIM 100   // NG*HID
#define GH 15
#define GW 15
#define BT 8       // batch tile per block

typedef _Float16 half2v __attribute__((ext_vector_type(2)));

#if defined(__has_builtin)
#if __has_builtin(__builtin_amdgcn_fdot2)
#define HAVE_FDOT2 1
#endif
#endif

__device__ __forceinline__ float fdot2f(half2v a, half2v b, float c) {
#ifdef HAVE_FDOT2
    return __builtin_amdgcn_fdot2(a, b, c, false);
#else
    return c + (float)a[0] * (float)b[0] + (float)a[1] * (float)b[1];
#endif
}

__device__ __forceinline__ float sigf(float x) {
    // safe both tails: exp(+inf)->inf, rcp(inf)->0 ; exp(-x)->0 -> rcp(1)=1
    return __builtin_amdgcn_rcpf(1.f + __expf(-x));
}
__device__ __forceinline__ float tanhfast(float x) {
    // overflow-safe: e = exp(-2|x|) in (0,1], restore sign (fixes NaN for x < -44)
    float ax = fabsf(x);
    float e = __expf(-2.f * ax);
    float t = (1.f - e) * __builtin_amdgcn_rcpf(1.f + e);
    return copysignf(t, x);
}

// ---------------- Kernel 1: conv3x3 + bias + maxpool2x2 + tanh -> f16 pairs ----------------
// x: [B,3,32,32] -> featH [B,225,6] half2 words: (c0,c1)(c2,c3)(c4,0)(c5,c6)(c7,c8)(c9,0)
__global__ __launch_bounds__(256) void conv_pool_tanh(
    const float* __restrict__ x,
    const float* __restrict__ conv_w,
    const float* __restrict__ conv_b,
    half2v* __restrict__ featH)
{
    __shared__ float wl[270];
    __shared__ float bl[10];
    int tid = threadIdx.x;
    for (int e = tid; e < 270; e += 256) wl[e] = conv_w[e];
    if (tid < 10) bl[tid] = conv_b[tid];
    __syncthreads();
    int gid = blockIdx.x * 256 + tid;
    if (gid >= NB * 225) return;
    int b = gid / 225;
    int r = gid % 225;
    int i = r / 15, j = r % 15;
    const float* xb = x + (size_t)b * 3 * 1024;

    float win[3][4][4];
    #pragma unroll
    for (int ic = 0; ic < 3; ++ic)
        #pragma unroll
        for (int rr = 0; rr < 4; ++rr)
            #pragma unroll
            for (int cc = 0; cc < 4; ++cc)
                win[ic][rr][cc] = xb[ic * 1024 + (2 * i + rr) * 32 + (2 * j + cc)];

    float vals[10];
    #pragma unroll
    for (int oc = 0; oc < CINC; ++oc) {
        float a00, a01, a10, a11;
        a00 = a01 = a10 = a11 = bl[oc];
        #pragma unroll
        for (int ic = 0; ic < 3; ++ic)
            #pragma unroll
            for (int kr = 0; kr < 3; ++kr)
                #pragma unroll
                for (int kc = 0; kc < 3; ++kc) {
                    float w = wl[(oc * 3 + ic) * 9 + kr * 3 + kc];
                    a00 += win[ic][kr][kc]         * w;
                    a01 += win[ic][kr][kc + 1]     * w;
                    a10 += win[ic][kr + 1][kc]     * w;
                    a11 += win[ic][kr + 1][kc + 1] * w;
                }
        float m = fmaxf(fmaxf(a00, a01), fmaxf(a10, a11));
        vals[oc] = tanhfast(m);
    }
    half2v* fo = featH + (size_t)gid * 6;
    half2v w0; w0[0] = (_Float16)vals[0]; w0[1] = (_Float16)vals[1]; fo[0] = w0;
    half2v w1; w1[0] = (_Float16)vals[2]; w1[1] = (_Float16)vals[3]; fo[1] = w1;
    half2v w2; w2[0] = (_Float16)vals[4]; w2[1] = (_Float16)0.f;     fo[2] = w2;
    half2v w3; w3[0] = (_Float16)vals[5]; w3[1] = (_Float16)vals[6]; fo[3] = w3;
    half2v w4; w4[0] = (_Float16)vals[7]; w4[1] = (_Float16)vals[8]; fo[4] = w4;
    half2v w5; w5[0] = (_Float16)vals[9]; w5[1] = (_Float16)0.f;     fo[5] = w5;
}

// ---------------- Kernel 2: 4-direction MD-LSTM scan (f16 dot2, 1 barrier/cell) ----------------
// Block = (direction, 8-batch tile). 320 threads = (b<8, j<20, s<2).
// s=0: h_up@Whu + Wx[c<5];  s=1: h_left@Whl + Wx[c>=5]. Combine via shfl_xor(1).
// Weights f16-packed in VGPRs (~70 regs); h history f16 in LDS, c fp32.
// Row state ping-pong (hUp/cUp) + column-parity left state (hLf/cLf) -> 1 barrier/cell.
__global__ __launch_bounds__(320, 4) void mdlstm_scan(
    const unsigned* __restrict__ featW,   // [B,225,6] u32 (half2 pairs)
    const float* __restrict__ Wx,         // [4,10,100]
    const float* __restrict__ Whu,        // [4,20,100]
    const float* __restrict__ Whl,        // [4,20,100]
    const float* __restrict__ bg,         // [4,100]
    float* __restrict__ corners)          // [B,80]
{
    int t = threadIdx.x;
    int s = t & 1;
    int j = (t >> 1) % HID;
    int b = t / (2 * HID);            // 0..7
    int d = blockIdx.y;
    int bglob = blockIdx.x * BT + b;
    int fh = (d == 1 || d == 3);
    int fw = (d == 2 || d == 3);

    // ---- f16-packed per-thread weights (fit in VGPRs: 50+15+5) ----
    half2v wA2[10][NG];
    const float* WM = (s == 0 ? Whu : Whl) + d * HID * GDIM;
    #pragma unroll
    for (int m = 0; m < 10; ++m)
        #pragma unroll
        for (int g = 0; g < NG; ++g) {
            half2v w;
            w[0] = (_Float16)WM[(2 * m)     * GDIM + g * HID + j];
            w[1] = (_Float16)WM[(2 * m + 1) * GDIM + g * HID + j];
            wA2[m][g] = w;
        }
    half2v wX2[3][NG];
    int cb = s * 5;
    #pragma unroll
    for (int p = 0; p < 3; ++p)
        #pragma unroll
        for (int g = 0; g < NG; ++g) {
            float w0 = Wx[d * CINC * GDIM + (cb + 2 * p) * GDIM + g * HID + j];
            float w1 = (p < 2) ? Wx[d * CINC * GDIM + (cb + 2 * p + 1) * GDIM + g * HID + j] : 0.f;
            half2v w; w[0] = (_Float16)w0; w[1] = (_Float16)w1;
            wX2[p][g] = w;
        }
    float bgr[NG];
    #pragma unroll
    for (int g = 0; g < NG; ++g) bgr[g] = bg[d * GDIM + g * HID + j];

    // ---- LDS state ----
    __shared__ _Float16 hUp[2][GW][BT][HID];   // 9.6 KB
    __shared__ float    cUp[2][GW][BT][HID];   // 19.2 KB
    __shared__ _Float16 hLf[2][BT][HID];       // 0.64 KB
    __shared__ float    cLf[2][BT][HID];       // 1.28 KB
    __shared__ unsigned fr[GW][BT][6];         // 2.88 KB

    // zero the buffers row 0 reads (ru = 1)
    for (int e = t; e < GW * BT * HID; e += 320) {
        (&hUp[1][0][0][0])[e] = (_Float16)0.f;
        (&cUp[1][0][0][0])[e] = 0.f;
    }

    for (int i = 0; i < GH; ++i) {
        int ru = (i & 1) ^ 1, wu = i & 1;
        int fi = fh ? (GH - 1 - i) : i;
        // stage feat row (W-flip applied); zero left-state parity 0 (read at jc=0)
        for (int e = t; e < GW * BT * 6; e += 320) {
            int col = e / (BT * 6);
            int rem = e % (BT * 6);
            int bb  = rem / 6;
            int w   = rem % 6;
            int fcol = fw ? (GW - 1 - col) : col;
            fr[col][bb][w] =
                featW[(((size_t)blockIdx.x * BT + bb) * 225 + fi * 15 + fcol) * 6 + w];
        }
        for (int e = t; e < BT * HID; e += 320) {
            (&hLf[0][0][0])[e] = (_Float16)0.f;
            (&cLf[0][0][0])[e] = 0.f;
        }

        for (int jc = 0; jc < GW; ++jc) {
            __syncthreads();   // prev cell's (or staging) writes visible
            int lp = jc & 1, wp = lp ^ 1;

            const half2v* hsrc = s ? (const half2v*)&hLf[lp][b][0]
                                   : (const half2v*)&hUp[ru][jc][b][0];
            half2v h2[10];
            #pragma unroll
            for (int m = 0; m < 10; ++m) h2[m] = hsrc[m];
            half2v f2[3];
            #pragma unroll
            for (int p = 0; p < 3; ++p)
                f2[p] = ((const half2v*)&fr[jc][b][0])[s * 3 + p];
            float cu = cUp[ru][jc][b][j];
            float cl = cLf[lp][b][j];

            float acc[NG];
            #pragma unroll
            for (int g = 0; g < NG; ++g) {
                float a = 0.f;
                #pragma unroll
                for (int m = 0; m < 10; ++m) a = fdot2f(h2[m], wA2[m][g], a);
                #pragma unroll
                for (int p = 0; p < 3; ++p)  a = fdot2f(f2[p], wX2[p][g], a);
                acc[g] = a;
            }

            float tot[NG];
            #pragma unroll
            for (int g = 0; g < NG; ++g)
                tot[g] = acc[g] + __shfl_xor(acc[g], 1) + bgr[g];
            float gi = sigf(tot[0]);
            float g1 = sigf(tot[1]);
            float g2 = sigf(tot[2]);
            float zz = tanhfast(tot[3]);
            float go = sigf(tot[4]);
            float cn = g1 * cu + g2 * cl + gi * zz;
            float hn = go * tanhfast(cn);

            if (s == 0) {
                hUp[wu][jc][b][j] = (_Float16)hn;
                cUp[wu][jc][b][j] = cn;
                hLf[wp][b][j] = (_Float16)hn;
                cLf[wp][b][j] = cn;
                if (i == GH - 1 && jc == GW - 1)
                    corners[(size_t)bglob * 80 + d * HID + j] = hn;
            }
        }
        __syncthreads();   // protect fr / lf from next row's staging
    }
}

// ---------------- Kernel 3: final FC [B,80] @ [80,10] + b ----------------
__global__ __launch_bounds__(256) void fc_kernel(
    const float* __restrict__ corners, // [B,80]
    const float* __restrict__ fc_w,    // [80,10]
    const float* __restrict__ fc_b,    // [10]
    float* __restrict__ out)           // [B,10]
{
    __shared__ float w[800];
    __shared__ float bb[10];
    int t = threadIdx.x;
    for (int e = t; e < 800; e += 256) w[e] = fc_w[e];
    if (t < 10) bb[t] = fc_b[t];
    __syncthreads();
    int gid = blockIdx.x * 256 + t;
    if (gid >= NB * 10) return;
    int b = gid / 10, o = gid % 10;
    float acc = bb[o];
    #pragma unroll 8
    for (int k = 0; k < 80; ++k)
        acc += corners[(size_t)b * 80 + k] * w[k * 10 + o];
    out[gid] = acc;
}

// ---------------- launcher ----------------
extern "C" void kernel_launch(void* const* d_in, const int* in_sizes, int n_in,
                              void* d_out, int out_size, void* d_ws, size_t ws_size,
                              hipStream_t stream) {
    const float* x      = (const float*)d_in[0];
    const float* conv_w = (const float*)d_in[1];
    const float* conv_b = (const float*)d_in[2];
    const float* Wx     = (const float*)d_in[3];
    const float* Whu    = (const float*)d_in[4];
    const float* Whl    = (const float*)d_in[5];
    const float* bg     = (const float*)d_in[6];
    const float* fc_w   = (const float*)d_in[7];
    const float* fc_b   = (const float*)d_in[8];
    float* out = (float*)d_out;

    half2v*   featH = (half2v*)d_ws;                       // B*225*6 half2 = 11.06 MB
    unsigned* featW = (unsigned*)d_ws;
    float* corners  = (float*)d_ws + (size_t)NB * 225 * 6; // B*80 floats

    conv_pool_tanh<<<dim3((NB * 225 + 255) / 256), 256, 0, stream>>>(x, conv_w, conv_b, featH);
    mdlstm_scan<<<dim3(NB / BT, 4), 320, 0, stream>>>(featW, Wx, Whu, Whl, bg, corners);
    fc_kernel<<<dim3((NB * 10 + 255) / 256), 256, 0, stream>>>(corners, fc_w, fc_b, out);
}

// Round 7
// 433.269 us; speedup vs baseline: 2.8738x; 1.5990x over previous
//
#include <hip/hip_runtime.h>
#include <math.h>

#define NB 2048
#define CINC 10
#define HID 20
#define NG 5
#define GDIM 100   // NG*HID
#define GH 15
#define GW 15
#define BW 3       // batch elems per wave (3*20 = 60 active lanes)

typedef _Float16 half2v __attribute__((ext_vector_type(2)));
typedef _Float16 half4v __attribute__((ext_vector_type(4)));
typedef _Float16 half8v __attribute__((ext_vector_type(8)));

#if defined(__has_builtin)
#if __has_builtin(__builtin_amdgcn_fdot2)
#define HAVE_FDOT2 1
#endif
#endif

__device__ __forceinline__ float fdot2f(half2v a, half2v b, float c) {
#ifdef HAVE_FDOT2
    return __builtin_amdgcn_fdot2(a, b, c, false);
#else
    return c + (float)a[0] * (float)b[0] + (float)a[1] * (float)b[1];
#endif
}

__device__ __forceinline__ float sigf(float x) {
    return __builtin_amdgcn_rcpf(1.f + __expf(-x));
}
__device__ __forceinline__ float tanhfast(float x) {
    // overflow-safe: e = exp(-2|x|) in (0,1], restore sign
    float ax = fabsf(x);
    float e = __expf(-2.f * ax);
    float t = (1.f - e) * __builtin_amdgcn_rcpf(1.f + e);
    return copysignf(t, x);
}

#define SV8(v, a, b) ((half2v)__builtin_shufflevector(v, v, a, b))
#define SV4(v, a, b) ((half2v)__builtin_shufflevector(v, v, a, b))

// ---------------- Kernel 1: conv3x3 + bias + maxpool2x2 + tanh -> f16 pairs ----------------
// x: [B,3,32,32] -> featH [B,225,12] halves: (c0,c1)(c2,c3)(c4,0)(c5,c6)(c7,c8)(c9,0)
__global__ __launch_bounds__(256) void conv_pool_tanh(
    const float* __restrict__ x,
    const float* __restrict__ conv_w,
    const float* __restrict__ conv_b,
    half2v* __restrict__ featH)
{
    __shared__ float wl[270];
    __shared__ float bl[10];
    int tid = threadIdx.x;
    for (int e = tid; e < 270; e += 256) wl[e] = conv_w[e];
    if (tid < 10) bl[tid] = conv_b[tid];
    __syncthreads();
    int gid = blockIdx.x * 256 + tid;
    if (gid >= NB * 225) return;
    int b = gid / 225;
    int r = gid % 225;
    int i = r / 15, j = r % 15;
    const float* xb = x + (size_t)b * 3 * 1024;

    float win[3][4][4];
    #pragma unroll
    for (int ic = 0; ic < 3; ++ic)
        #pragma unroll
        for (int rr = 0; rr < 4; ++rr)
            #pragma unroll
            for (int cc = 0; cc < 4; ++cc)
                win[ic][rr][cc] = xb[ic * 1024 + (2 * i + rr) * 32 + (2 * j + cc)];

    float vals[10];
    #pragma unroll
    for (int oc = 0; oc < CINC; ++oc) {
        float a00, a01, a10, a11;
        a00 = a01 = a10 = a11 = bl[oc];
        #pragma unroll
        for (int ic = 0; ic < 3; ++ic)
            #pragma unroll
            for (int kr = 0; kr < 3; ++kr)
                #pragma unroll
                for (int kc = 0; kc < 3; ++kc) {
                    float w = wl[(oc * 3 + ic) * 9 + kr * 3 + kc];
                    a00 += win[ic][kr][kc]         * w;
                    a01 += win[ic][kr][kc + 1]     * w;
                    a10 += win[ic][kr + 1][kc]     * w;
                    a11 += win[ic][kr + 1][kc + 1] * w;
                }
        float m = fmaxf(fmaxf(a00, a01), fmaxf(a10, a11));
        vals[oc] = tanhfast(m);
    }
    half2v* fo = featH + (size_t)gid * 6;
    half2v w0; w0[0] = (_Float16)vals[0]; w0[1] = (_Float16)vals[1]; fo[0] = w0;
    half2v w1; w1[0] = (_Float16)vals[2]; w1[1] = (_Float16)vals[3]; fo[1] = w1;
    half2v w2; w2[0] = (_Float16)vals[4]; w2[1] = (_Float16)0.f;     fo[2] = w2;
    half2v w3; w3[0] = (_Float16)vals[5]; w3[1] = (_Float16)vals[6]; fo[3] = w3;
    half2v w4; w4[0] = (_Float16)vals[7]; w4[1] = (_Float16)vals[8]; fo[4] = w4;
    half2v w5; w5[0] = (_Float16)vals[9]; w5[1] = (_Float16)0.f;     fo[5] = w5;
}

// ---------------- Kernel 2: barrier-free wave-private MD-LSTM scan ----------------
// Block = 1 wave = (direction, 3-batch tile). lane = (b<3, j<20); 4 lanes idle.
// Each lane computes all 5 gates for its (b,j): no shfl, no __syncthreads.
// h f16 ping-pong row buffer (col 0 = permanent zeros = left state at jc=0);
// c f32 row history in LDS; c_left in a register.
__global__ __launch_bounds__(64) void mdlstm_scan(
    const _Float16* __restrict__ featF,   // [B,225,12] halves
    const float* __restrict__ Wx,         // [4,10,100]
    const float* __restrict__ Whu,        // [4,20,100]
    const float* __restrict__ Whl,        // [4,20,100]
    const float* __restrict__ bg,         // [4,100]
    float* __restrict__ corners)          // [B,80]
{
    int t = threadIdx.x;
    int b = t / HID;              // 0..2 active, 3 for idle lanes
    int j = t % HID;
    bool act = (t < BW * HID);
    int bl = act ? b : 0;         // safe LDS index for idle lanes
    int d = blockIdx.y;
    int bglob = blockIdx.x * BW + b;
    bool bval = act && (bglob < NB);
    int fh = (d == 1 || d == 3);
    int fw = (d == 2 || d == 3);

    // ---- f16-packed weights in registers ----
    half2v wU[10][NG], wL[10][NG], wX2[6][NG];
    {
        const float* WU = Whu + d * HID * GDIM;
        const float* WL = Whl + d * HID * GDIM;
        #pragma unroll
        for (int m = 0; m < 10; ++m)
            #pragma unroll
            for (int g = 0; g < NG; ++g) {
                int cidx = g * HID + j;
                half2v w; w[0] = (_Float16)WU[(2*m)*GDIM + cidx]; w[1] = (_Float16)WU[(2*m+1)*GDIM + cidx];
                wU[m][g] = w;
                half2v v; v[0] = (_Float16)WL[(2*m)*GDIM + cidx]; v[1] = (_Float16)WL[(2*m+1)*GDIM + cidx];
                wL[m][g] = v;
            }
        const int cha[6] = {0, 2, 4, 5, 7, 9};
        const int chb[6] = {1, 3, -1, 6, 8, -1};
        const float* WXp = Wx + d * CINC * GDIM;
        #pragma unroll
        for (int w = 0; w < 6; ++w)
            #pragma unroll
            for (int g = 0; g < NG; ++g) {
                int cidx = g * HID + j;
                half2v v;
                v[0] = (_Float16)WXp[cha[w] * GDIM + cidx];
                v[1] = (chb[w] >= 0) ? (_Float16)WXp[chb[w] * GDIM + cidx] : (_Float16)0.f;
                wX2[w][g] = v;
            }
    }
    float bgr[NG];
    #pragma unroll
    for (int g = 0; g < NG; ++g) bgr[g] = bg[d * GDIM + g * HID + j];

    // ---- LDS (wave-private; ~9.7 KB) ----
    __shared__ _Float16 hR[2][GW + 1][BW][24];  // 48B per (col,b); col 0 = zeros
    __shared__ float    cR[GW][BW][HID];
    __shared__ _Float16 fr[GW][BW][16];         // 32B per (col,b); halves 0..11 valid

    for (int e = t; e < 2 * (GW + 1) * BW * 24; e += 64) (&hR[0][0][0][0])[e] = (_Float16)0.f;
    for (int e = t; e < GW * BW * HID; e += 64) (&cR[0][0][0])[e] = 0.f;

    for (int i = 0; i < GH; ++i) {
        int p = i & 1, q = p ^ 1;
        int fi = fh ? (GH - 1 - i) : i;
        // stage this row's feat words (W-flip applied)
        for (int e = t; e < GW * BW * 6; e += 64) {
            int col = e / (BW * 6);
            int rem = e % (BW * 6);
            int bb  = rem / 6;
            int w   = rem % 6;
            int bs  = blockIdx.x * BW + bb; if (bs >= NB) bs = NB - 1;
            int fcol = fw ? (GW - 1 - col) : col;
            ((unsigned*)fr)[(col * BW + bb) * 8 + w] =
                ((const unsigned*)featF)[((size_t)bs * 225 + fi * 15 + fcol) * 6 + w];
        }
        float cl = 0.f;

        #pragma unroll 5
        for (int jc = 0; jc < GW; ++jc) {
            const _Float16* hu_p = &hR[q][jc + 1][bl][0];
            const _Float16* hl_p = &hR[p][jc][bl][0];
            half8v u0 = *(const half8v*)(hu_p);
            half8v u1 = *(const half8v*)(hu_p + 8);
            half4v u2 = *(const half4v*)(hu_p + 16);
            half8v l0 = *(const half8v*)(hl_p);
            half8v l1 = *(const half8v*)(hl_p + 8);
            half4v l2 = *(const half4v*)(hl_p + 16);
            half8v x0 = *(const half8v*)&fr[jc][bl][0];
            half4v x1 = *(const half4v*)&fr[jc][bl][8];
            float cu = cR[jc][bl][j];

            half2v up[10] = { SV8(u0,0,1), SV8(u0,2,3), SV8(u0,4,5), SV8(u0,6,7),
                              SV8(u1,0,1), SV8(u1,2,3), SV8(u1,4,5), SV8(u1,6,7),
                              SV4(u2,0,1), SV4(u2,2,3) };
            half2v lf[10] = { SV8(l0,0,1), SV8(l0,2,3), SV8(l0,4,5), SV8(l0,6,7),
                              SV8(l1,0,1), SV8(l1,2,3), SV8(l1,4,5), SV8(l1,6,7),
                              SV4(l2,0,1), SV4(l2,2,3) };
            half2v xp[6]  = { SV8(x0,0,1), SV8(x0,2,3), SV8(x0,4,5), SV8(x0,6,7),
                              SV4(x1,0,1), SV4(x1,2,3) };

            float acc[NG];
            #pragma unroll
            for (int g = 0; g < NG; ++g) acc[g] = bgr[g];
            #pragma unroll
            for (int m = 0; m < 10; ++m)
                #pragma unroll
                for (int g = 0; g < NG; ++g) acc[g] = fdot2f(up[m], wU[m][g], acc[g]);
            #pragma unroll
            for (int m = 0; m < 10; ++m)
                #pragma unroll
                for (int g = 0; g < NG; ++g) acc[g] = fdot2f(lf[m], wL[m][g], acc[g]);
            #pragma unroll
            for (int w = 0; w < 6; ++w)
                #pragma unroll
                for (int g = 0; g < NG; ++g) acc[g] = fdot2f(xp[w], wX2[w][g], acc[g]);

            float gi = sigf(acc[0]);
            float g1 = sigf(acc[1]);
            float g2 = sigf(acc[2]);
            float zz = tanhfast(acc[3]);
            float go = sigf(acc[4]);
            float cn = g1 * cu + g2 * cl + gi * zz;
            float hn = go * tanhfast(cn);

            if (act) {
                hR[p][jc + 1][bl][j] = (_Float16)hn;
                cR[jc][bl][j] = cn;
            }
            cl = cn;
            if (bval && i == GH - 1 && jc == GW - 1)
                corners[(size_t)bglob * 80 + d * HID + j] = hn;
        }
    }
}

// ---------------- Kernel 3: final FC [B,80] @ [80,10] + b ----------------
__global__ __launch_bounds__(256) void fc_kernel(
    const float* __restrict__ corners, // [B,80]
    const float* __restrict__ fc_w,    // [80,10]
    const float* __restrict__ fc_b,    // [10]
    float* __restrict__ out)           // [B,10]
{
    __shared__ float w[800];
    __shared__ float bb[10];
    int t = threadIdx.x;
    for (int e = t; e < 800; e += 256) w[e] = fc_w[e];
    if (t < 10) bb[t] = fc_b[t];
    __syncthreads();
    int gid = blockIdx.x * 256 + t;
    if (gid >= NB * 10) return;
    int b = gid / 10, o = gid % 10;
    float acc = bb[o];
    #pragma unroll 8
    for (int k = 0; k < 80; ++k)
        acc += corners[(size_t)b * 80 + k] * w[k * 10 + o];
    out[gid] = acc;
}

// ---------------- launcher ----------------
extern "C" void kernel_launch(void* const* d_in, const int* in_sizes, int n_in,
                              void* d_out, int out_size, void* d_ws, size_t ws_size,
                              hipStream_t stream) {
    const float* x      = (const float*)d_in[0];
    const float* conv_w = (const float*)d_in[1];
    const float* conv_b = (const float*)d_in[2];
    const float* Wx     = (const float*)d_in[3];
    const float* Whu    = (const float*)d_in[4];
    const float* Whl    = (const float*)d_in[5];
    const float* bg     = (const float*)d_in[6];
    const float* fc_w   = (const float*)d_in[7];
    const float* fc_b   = (const float*)d_in[8];
    float* out = (float*)d_out;

    half2v*    featH = (half2v*)d_ws;                       // B*225*6 half2 = 11.06 MB
    _Float16*  featF = (_Float16*)d_ws;
    float* corners   = (float*)d_ws + (size_t)NB * 225 * 6; // B*80 floats

    conv_pool_tanh<<<dim3((NB * 225 + 255) / 256), 256, 0, stream>>>(x, conv_w, conv_b, featH);
    mdlstm_scan<<<dim3((NB + BW - 1) / BW, 4), 64, 0, stream>>>(featF, Wx, Whu, Whl, bg, corners);
    fc_kernel<<<dim3((NB * 10 + 255) / 256), 256, 0, stream>>>(corners, fc_w, fc_b, out);
}